// Round 7
// baseline (126.848 us; speedup 1.0000x reference)
//
#include <hip/hip_runtime.h>
#include <hip/hip_bf16.h>
#include <hip/hip_fp16.h>

// Problem constants
#define DM   256
#define NH   8
#define HC   32
#define SEQ  512
#define MTOT 1024

// ---------- workspace layout (byte offsets) ----------
#define B_X1   0            // fp32 x1 [1024][256]      1 MB
#define B_QH   (1u<<20)     // fp16 q  [16][512][32]    512 KB
#define B_KH   0x180000u    // fp16 k  [16][512][32]    512 KB
#define B_VT   0x200000u    // bf16 vT [16][32][512]    512 KB
#define B_WFCT 0x280000u    // bf16 WfcT  [1024][256]   512 KB
#define B_WPJT 0x300000u    // bf16 WprojT [256][1024]  512 KB

typedef __attribute__((ext_vector_type(8))) __bf16 bf16x8;
typedef __attribute__((ext_vector_type(4))) __bf16 bf16x4;
typedef __attribute__((ext_vector_type(4))) float  f32x4;

__device__ __forceinline__ float qgelu(float x) {
    return x / (1.0f + __expf(-1.702f * x));
}

// ---------------------------------------------------------------------------
// K1: QKV GEMM (1024x768, K=256) + side-car weight transposes.
// Blocks 0..767: one 16x16 MFMA tile per wave. A = fp32 x cvt in-reg;
// B = strided fp32 loads from W_qkv. Epilogue: +bias, q/k fp16, v bf16 V^T.
// Blocks 768..895: LDS-tiled 64x64 transposes of Wfc/Wproj -> bf16 [n][k].
// ---------------------------------------------------------------------------
__global__ __launch_bounds__(256)
void qkv_k(const float* __restrict__ x, const float* __restrict__ W,
           const float* __restrict__ bias,
           const float* __restrict__ Wfc, const float* __restrict__ Wproj,
           char* __restrict__ wsb)
{
    __shared__ float lt[64 * 65];
    const int bid = blockIdx.x, tid = threadIdx.x;

    if (bid >= 768) {
        const int tt = bid - 768;
        const float* src; __bf16* dst; int K, N, tile;
        if (tt < 64) { src = Wfc;   dst = (__bf16*)(wsb + B_WFCT); K = 256;  N = 1024; tile = tt; }
        else         { src = Wproj; dst = (__bf16*)(wsb + B_WPJT); K = 1024; N = 256;  tile = tt - 64; }
        const int nn = N >> 6;
        const int k0 = (tile / nn) * 64, n0 = (tile % nn) * 64;
        const int rr0 = tid >> 4, c4 = tid & 15;
        #pragma unroll
        for (int i = 0; i < 4; ++i) {
            const int rr = rr0 + i * 16;
            float4 v = *(const float4*)&src[(size_t)(k0 + rr) * N + n0 + c4 * 4];
            lt[rr * 65 + c4 * 4 + 0] = v.x; lt[rr * 65 + c4 * 4 + 1] = v.y;
            lt[rr * 65 + c4 * 4 + 2] = v.z; lt[rr * 65 + c4 * 4 + 3] = v.w;
        }
        __syncthreads();
        #pragma unroll
        for (int i = 0; i < 4; ++i) {
            const int rr = rr0 + i * 16;
            bf16x4 b;
            b.x = (__bf16)lt[(c4 * 4 + 0) * 65 + rr];
            b.y = (__bf16)lt[(c4 * 4 + 1) * 65 + rr];
            b.z = (__bf16)lt[(c4 * 4 + 2) * 65 + rr];
            b.w = (__bf16)lt[(c4 * 4 + 3) * 65 + rr];
            *(bf16x4*)&dst[(size_t)(n0 + rr) * K + k0 + c4 * 4] = b;
        }
        return;
    }

    const int lane = tid & 63, wv = tid >> 6;
    const int widx = bid * 4 + wv;               // 0..3071
    const int m0 = (widx & 63) * 16, n0 = (widx >> 6) * 16;
    const int r = lane & 15, q = lane >> 4;

    const float* ap = x + (size_t)(m0 + r) * DM + q * 8;
    const float* bp = W + (size_t)(q * 8) * 768 + n0 + r;

    f32x4 acc = {0.f, 0.f, 0.f, 0.f};
    #pragma unroll
    for (int kt = 0; kt < DM; kt += 32) {
        float4 a0 = *(const float4*)(ap + kt);
        float4 a1 = *(const float4*)(ap + kt + 4);
        bf16x8 af;
        af[0] = (__bf16)a0.x; af[1] = (__bf16)a0.y; af[2] = (__bf16)a0.z; af[3] = (__bf16)a0.w;
        af[4] = (__bf16)a1.x; af[5] = (__bf16)a1.y; af[6] = (__bf16)a1.z; af[7] = (__bf16)a1.w;
        bf16x8 bf;
        #pragma unroll
        for (int j = 0; j < 8; ++j)
            bf[j] = (__bf16)bp[(size_t)(kt + j) * 768];
        acc = __builtin_amdgcn_mfma_f32_16x16x32_bf16(af, bf, acc, 0, 0, 0);
    }

    __half*  qh  = (__half*)(wsb + B_QH);
    __half*  kh  = (__half*)(wsb + B_KH);
    __bf16*  vtb = (__bf16*)(wsb + B_VT);
    const int n = n0 + r;                 // C col = lane&15
    const float bn = bias[n];
    const int h = n / 96, jj = n % 96;
    #pragma unroll
    for (int i = 0; i < 4; ++i) {
        const int m = m0 + q * 4 + i;     // C row = q*4 + i
        const float v = acc[i] + bn;
        const int b = m >> 9, t = m & 511;
        const int bh = b * NH + h;
        if (jj < 32)      qh[((size_t)(bh * SEQ + t)) * HC + jj]        = (__half)v;
        else if (jj < 64) kh[((size_t)(bh * SEQ + t)) * HC + (jj - 32)] = (__half)v;
        else              vtb[((size_t)(bh * HC + (jj - 64))) * SEQ + t] = (__bf16)v;
    }
}

// ---------------------------------------------------------------------------
// K2: L1-distance attention + residual, fp16-packed distance (round-6 proven).
// ---------------------------------------------------------------------------
#define QT 16
#define PSTRIDE 514

__global__ __launch_bounds__(512, 4)
void attn_k(const char* __restrict__ wsb, const float* __restrict__ xin,
            float* __restrict__ x1)
{
    __shared__ __half2 qtile[QT * 16];
    __shared__ __bf16  pmat[QT * PSTRIDE];
    __shared__ float   psum[QT * 8];
    __shared__ float   pinv[QT];

    const __half*  qhg = (const __half*)(wsb + B_QH);
    const __half*  khg = (const __half*)(wsb + B_KH);
    const __bf16*  vtb = (const __bf16*)(wsb + B_VT);

    const int tid  = threadIdx.x;
    const int lane = tid & 63;
    const int wv   = tid >> 6;
    const int sg   = tid;                       // s index
    const int bh   = blockIdx.x >> 5;
    const int qbase = (blockIdx.x & 31) * QT;
    const float scale = 0.17677669529663687f;   // 1/sqrt(32)

    const __half2* kp = (const __half2*)(khg + ((size_t)(bh * SEQ + sg)) * HC);
    __half2 kr[16];
    #pragma unroll
    for (int j = 0; j < 16; ++j) kr[j] = kp[j];

    if (tid < 256) {
        const int t = tid >> 4, j = tid & 15;
        qtile[t * 16 + j] =
            *(const __half2*)(qhg + ((size_t)(bh * SEQ + qbase + t)) * HC + j * 2);
    }
    __syncthreads();

    #pragma unroll 4
    for (int t = 0; t < QT; ++t) {
        __half2 acc2 = __floats2half2_rn(0.f, 0.f);
        #pragma unroll
        for (int j = 0; j < 16; ++j) {
            __half2 dif = __hsub2(kr[j], qtile[t * 16 + j]);   // LDS broadcast
            unsigned u = (*(unsigned*)&dif) & 0x7FFF7FFFu;     // packed |.|
            acc2 = __hadd2(acc2, *(__half2*)&u);
        }
        const float d = __low2float(acc2) + __high2float(acc2);
        float w = 1.0f / (0.001f + d * scale);
        if (sg == qbase + t) w = 0.0f;          // diagonal
        float p = __expf(w);                    // w bounded: no max pass
        float se = p;
        #pragma unroll
        for (int off = 32; off >= 1; off >>= 1) se += __shfl_xor(se, off, 64);
        pmat[t * PSTRIDE + sg] = (__bf16)p;
        if (lane == 0) psum[t * 8 + wv] = se;
    }
    __syncthreads();

    if (tid < QT) {
        float s = 0.f;
        #pragma unroll
        for (int j = 0; j < 8; ++j) s += psum[tid * 8 + j];
        pinv[tid] = 1.0f / s;
    }
    __syncthreads();

    if (wv < 2) {
        const int r = lane & 15, q = lane >> 4;
        const __bf16* bp  = vtb + ((size_t)(bh * HC + wv * 16 + r)) * SEQ + q * 8;
        const __bf16* apm = &pmat[r * PSTRIDE + q * 8];
        f32x4 acc = {0.f, 0.f, 0.f, 0.f};
        #pragma unroll
        for (int kt = 0; kt < SEQ; kt += 32) {
            bf16x8 af = *(const bf16x8*)(apm + kt);
            bf16x8 bf = *(const bf16x8*)(bp + kt);
            acc = __builtin_amdgcn_mfma_f32_16x16x32_bf16(af, bf, acc, 0, 0, 0);
        }
        const int b = bh >> 3, hh = bh & 7;
        const int c = wv * 16 + r;
        #pragma unroll
        for (int i = 0; i < 4; ++i) {
            const int tl = q * 4 + i;
            const int t  = qbase + tl;
            const float v = acc[i] * pinv[tl];
            const int idx = ((b * SEQ + t) * DM) + hh * HC + c;
            x1[idx] = xin[idx] + v;
        }
    }
}

// ---------------------------------------------------------------------------
// K3: fused MLP. Block owns 16 rows: h = qgelu(x1 @ Wfc + b) -> LDS bf16
// [16][1032] (pad 8 -> 2-way banks on both write and b128 read = free),
// then out = x1 + h @ Wproj + b straight from LDS. 64 blocks x 512 threads.
// FC: wave w -> n-tiles w*8..w*8+7 (K=256). PROJ: wave w -> n-tiles
// w*2, w*2+1 (K=1024, A-frags via ds_read_b128).
// ---------------------------------------------------------------------------
#define HSTR 1032

__global__ __launch_bounds__(512)
void mlp_k(const float* __restrict__ X1, const char* __restrict__ wsb,
           const float* __restrict__ bfc, const float* __restrict__ bproj,
           float* __restrict__ out)
{
    __shared__ __bf16 hl[16 * HSTR];   // 33 KB
    const __bf16* Wf = (const __bf16*)(wsb + B_WFCT);
    const __bf16* Wp = (const __bf16*)(wsb + B_WPJT);

    const int tid  = threadIdx.x;
    const int lane = tid & 63;
    const int wv   = tid >> 6;
    const int m0   = blockIdx.x * 16;
    const int r    = lane & 15, q = lane >> 4;

    // ---- FC phase: h[16][1024] ----
    {
        const float* ap = X1 + (size_t)(m0 + r) * DM + q * 8;
        f32x4 acc[8] = {};
        #pragma unroll
        for (int kt = 0; kt < DM; kt += 32) {
            float4 a0 = *(const float4*)(ap + kt);
            float4 a1 = *(const float4*)(ap + kt + 4);
            bf16x8 af;
            af[0] = (__bf16)a0.x; af[1] = (__bf16)a0.y; af[2] = (__bf16)a0.z; af[3] = (__bf16)a0.w;
            af[4] = (__bf16)a1.x; af[5] = (__bf16)a1.y; af[6] = (__bf16)a1.z; af[7] = (__bf16)a1.w;
            #pragma unroll
            for (int nt = 0; nt < 8; ++nt) {
                const int n0 = (wv * 8 + nt) * 16;
                bf16x8 bf = *(const bf16x8*)(Wf + (size_t)(n0 + r) * DM + q * 8 + kt);
                acc[nt] = __builtin_amdgcn_mfma_f32_16x16x32_bf16(af, bf, acc[nt], 0, 0, 0);
            }
        }
        #pragma unroll
        for (int nt = 0; nt < 8; ++nt) {
            const int n = (wv * 8 + nt) * 16 + r;
            const float bn = bfc[n];
            #pragma unroll
            for (int i = 0; i < 4; ++i)
                hl[(q * 4 + i) * HSTR + n] = (__bf16)qgelu(acc[nt][i] + bn);
        }
    }
    __syncthreads();

    // ---- PROJ phase: out[16][256] ----
    {
        f32x4 acc[2] = {};
        const __bf16* al = &hl[r * HSTR + q * 8];
        #pragma unroll 4
        for (int kt = 0; kt < 1024; kt += 32) {
            bf16x8 af = *(const bf16x8*)(al + kt);
            #pragma unroll
            for (int nt = 0; nt < 2; ++nt) {
                const int n0 = (wv * 2 + nt) * 16;
                bf16x8 bf = *(const bf16x8*)(Wp + (size_t)(n0 + r) * 1024 + q * 8 + kt);
                acc[nt] = __builtin_amdgcn_mfma_f32_16x16x32_bf16(af, bf, acc[nt], 0, 0, 0);
            }
        }
        #pragma unroll
        for (int nt = 0; nt < 2; ++nt) {
            const int n = (wv * 2 + nt) * 16 + r;
            const float bn = bproj[n];
            #pragma unroll
            for (int i = 0; i < 4; ++i) {
                const int m = m0 + q * 4 + i;
                out[(size_t)m * DM + n] =
                    X1[(size_t)m * DM + n] + acc[nt][i] + bn;
            }
        }
    }
}

// ---------------------------------------------------------------------------
extern "C" void kernel_launch(void* const* d_in, const int* in_sizes, int n_in,
                              void* d_out, int out_size, void* d_ws, size_t ws_size,
                              hipStream_t stream)
{
    (void)in_sizes; (void)n_in; (void)out_size; (void)ws_size;
    const float* x     = (const float*)d_in[0];
    const float* Wqkv  = (const float*)d_in[1];
    const float* bqkv  = (const float*)d_in[2];
    const float* Wfc   = (const float*)d_in[3];
    const float* bfc   = (const float*)d_in[4];
    const float* Wproj = (const float*)d_in[5];
    const float* bproj = (const float*)d_in[6];
    float* out = (float*)d_out;
    char*  wsb = (char*)d_ws;
    float* x1  = (float*)(wsb + B_X1);

    // K1: QKV GEMM (strided W) + side-car Wfc/Wproj transposes
    qkv_k<<<896, 256, 0, stream>>>(x, Wqkv, bqkv, Wfc, Wproj, wsb);

    // K2: attention + residual -> x1 fp32
    attn_k<<<512, 512, 0, stream>>>(wsb, x, x1);

    // K3: out = x1 + qgelu(x1@Wfc+b) @ Wproj + b   (h stays in LDS)
    mlp_k<<<64, 512, 0, stream>>>(x1, wsb, bfc, bproj, out);
}

// Round 8
// 106.537 us; speedup vs baseline: 1.1906x; 1.1906x over previous
//
#include <hip/hip_runtime.h>
#include <hip/hip_bf16.h>
#include <hip/hip_fp16.h>

// Problem constants
#define DM   256
#define NH   8
#define HC   32
#define SEQ  512
#define MTOT 1024

// ---------- workspace layout (byte offsets) ----------
#define B_X1   0            // fp32 x1 [1024][256]      1 MB
#define B_QH   (1u<<20)     // fp16 q  [16][512][32]    512 KB
#define B_KH   0x180000u    // fp16 k  [16][512][32]    512 KB
#define B_VT   0x200000u    // bf16 vT [16][32][512]    512 KB
#define B_WFCT 0x280000u    // bf16 WfcT  [1024][256]   512 KB
#define B_WPJT 0x300000u    // bf16 WprojT [256][1024]  512 KB

typedef __attribute__((ext_vector_type(8))) __bf16 bf16x8;
typedef __attribute__((ext_vector_type(4))) __bf16 bf16x4;
typedef __attribute__((ext_vector_type(4))) float  f32x4;

__device__ __forceinline__ float qgelu(float x) {
    return x / (1.0f + __expf(-1.702f * x));
}

// ---------------------------------------------------------------------------
// K1: QKV GEMM (1024x768, K=256) + side-car weight transposes (round-6 proven).
// Blocks 0..767: one 16x16 MFMA tile per wave. A = fp32 x cvt in-reg;
// B = strided fp32 loads from W_qkv. Epilogue: +bias, q/k fp16, v bf16 V^T.
// Blocks 768..895: LDS-tiled 64x64 transposes of Wfc/Wproj -> bf16 [n][k].
// ---------------------------------------------------------------------------
__global__ __launch_bounds__(256)
void qkv_k(const float* __restrict__ x, const float* __restrict__ W,
           const float* __restrict__ bias,
           const float* __restrict__ Wfc, const float* __restrict__ Wproj,
           char* __restrict__ wsb)
{
    __shared__ float lt[64 * 65];
    const int bid = blockIdx.x, tid = threadIdx.x;

    if (bid >= 768) {
        const int tt = bid - 768;
        const float* src; __bf16* dst; int K, N, tile;
        if (tt < 64) { src = Wfc;   dst = (__bf16*)(wsb + B_WFCT); K = 256;  N = 1024; tile = tt; }
        else         { src = Wproj; dst = (__bf16*)(wsb + B_WPJT); K = 1024; N = 256;  tile = tt - 64; }
        const int nn = N >> 6;
        const int k0 = (tile / nn) * 64, n0 = (tile % nn) * 64;
        const int rr0 = tid >> 4, c4 = tid & 15;
        #pragma unroll
        for (int i = 0; i < 4; ++i) {
            const int rr = rr0 + i * 16;
            float4 v = *(const float4*)&src[(size_t)(k0 + rr) * N + n0 + c4 * 4];
            lt[rr * 65 + c4 * 4 + 0] = v.x; lt[rr * 65 + c4 * 4 + 1] = v.y;
            lt[rr * 65 + c4 * 4 + 2] = v.z; lt[rr * 65 + c4 * 4 + 3] = v.w;
        }
        __syncthreads();
        #pragma unroll
        for (int i = 0; i < 4; ++i) {
            const int rr = rr0 + i * 16;
            bf16x4 b;
            b.x = (__bf16)lt[(c4 * 4 + 0) * 65 + rr];
            b.y = (__bf16)lt[(c4 * 4 + 1) * 65 + rr];
            b.z = (__bf16)lt[(c4 * 4 + 2) * 65 + rr];
            b.w = (__bf16)lt[(c4 * 4 + 3) * 65 + rr];
            *(bf16x4*)&dst[(size_t)(n0 + rr) * K + k0 + c4 * 4] = b;
        }
        return;
    }

    const int lane = tid & 63, wv = tid >> 6;
    const int widx = bid * 4 + wv;               // 0..3071
    const int m0 = (widx & 63) * 16, n0 = (widx >> 6) * 16;
    const int r = lane & 15, q = lane >> 4;

    const float* ap = x + (size_t)(m0 + r) * DM + q * 8;
    const float* bp = W + (size_t)(q * 8) * 768 + n0 + r;

    f32x4 acc = {0.f, 0.f, 0.f, 0.f};
    #pragma unroll
    for (int kt = 0; kt < DM; kt += 32) {
        float4 a0 = *(const float4*)(ap + kt);
        float4 a1 = *(const float4*)(ap + kt + 4);
        bf16x8 af;
        af[0] = (__bf16)a0.x; af[1] = (__bf16)a0.y; af[2] = (__bf16)a0.z; af[3] = (__bf16)a0.w;
        af[4] = (__bf16)a1.x; af[5] = (__bf16)a1.y; af[6] = (__bf16)a1.z; af[7] = (__bf16)a1.w;
        bf16x8 bf;
        #pragma unroll
        for (int j = 0; j < 8; ++j)
            bf[j] = (__bf16)bp[(size_t)(kt + j) * 768];
        acc = __builtin_amdgcn_mfma_f32_16x16x32_bf16(af, bf, acc, 0, 0, 0);
    }

    __half*  qh  = (__half*)(wsb + B_QH);
    __half*  kh  = (__half*)(wsb + B_KH);
    __bf16*  vtb = (__bf16*)(wsb + B_VT);
    const int n = n0 + r;                 // C col = lane&15
    const float bn = bias[n];
    const int h = n / 96, jj = n % 96;
    #pragma unroll
    for (int i = 0; i < 4; ++i) {
        const int m = m0 + q * 4 + i;     // C row = q*4 + i
        const float v = acc[i] + bn;
        const int b = m >> 9, t = m & 511;
        const int bh = b * NH + h;
        if (jj < 32)      qh[((size_t)(bh * SEQ + t)) * HC + jj]        = (__half)v;
        else if (jj < 64) kh[((size_t)(bh * SEQ + t)) * HC + (jj - 32)] = (__half)v;
        else              vtb[((size_t)(bh * HC + (jj - 64))) * SEQ + t] = (__bf16)v;
    }
}

// ---------------------------------------------------------------------------
// K2: L1-distance attention + residual, fp16-packed distance (round-6 proven)
// + NEW: pre-initializes out = x1 + bproj (base for K3's atomic partials).
// ---------------------------------------------------------------------------
#define QT 16
#define PSTRIDE 514

__global__ __launch_bounds__(512, 4)
void attn_k(const char* __restrict__ wsb, const float* __restrict__ xin,
            float* __restrict__ x1, const float* __restrict__ bproj,
            float* __restrict__ out)
{
    __shared__ __half2 qtile[QT * 16];
    __shared__ __bf16  pmat[QT * PSTRIDE];
    __shared__ float   psum[QT * 8];
    __shared__ float   pinv[QT];

    const __half*  qhg = (const __half*)(wsb + B_QH);
    const __half*  khg = (const __half*)(wsb + B_KH);
    const __bf16*  vtb = (const __bf16*)(wsb + B_VT);

    const int tid  = threadIdx.x;
    const int lane = tid & 63;
    const int wv   = tid >> 6;
    const int sg   = tid;                       // s index
    const int bh   = blockIdx.x >> 5;
    const int qbase = (blockIdx.x & 31) * QT;
    const float scale = 0.17677669529663687f;   // 1/sqrt(32)

    const __half2* kp = (const __half2*)(khg + ((size_t)(bh * SEQ + sg)) * HC);
    __half2 kr[16];
    #pragma unroll
    for (int j = 0; j < 16; ++j) kr[j] = kp[j];

    if (tid < 256) {
        const int t = tid >> 4, j = tid & 15;
        qtile[t * 16 + j] =
            *(const __half2*)(qhg + ((size_t)(bh * SEQ + qbase + t)) * HC + j * 2);
    }
    __syncthreads();

    #pragma unroll 4
    for (int t = 0; t < QT; ++t) {
        __half2 acc2 = __floats2half2_rn(0.f, 0.f);
        #pragma unroll
        for (int j = 0; j < 16; ++j) {
            __half2 dif = __hsub2(kr[j], qtile[t * 16 + j]);   // LDS broadcast
            unsigned u = (*(unsigned*)&dif) & 0x7FFF7FFFu;     // packed |.|
            acc2 = __hadd2(acc2, *(__half2*)&u);
        }
        const float d = __low2float(acc2) + __high2float(acc2);
        float w = 1.0f / (0.001f + d * scale);
        if (sg == qbase + t) w = 0.0f;          // diagonal
        float p = __expf(w);                    // w bounded: no max pass
        float se = p;
        #pragma unroll
        for (int off = 32; off >= 1; off >>= 1) se += __shfl_xor(se, off, 64);
        pmat[t * PSTRIDE + sg] = (__bf16)p;
        if (lane == 0) psum[t * 8 + wv] = se;
    }
    __syncthreads();

    if (tid < QT) {
        float s = 0.f;
        #pragma unroll
        for (int j = 0; j < 8; ++j) s += psum[tid * 8 + j];
        pinv[tid] = 1.0f / s;
    }
    __syncthreads();

    if (wv < 2) {
        const int r = lane & 15, q = lane >> 4;
        const __bf16* bp  = vtb + ((size_t)(bh * HC + wv * 16 + r)) * SEQ + q * 8;
        const __bf16* apm = &pmat[r * PSTRIDE + q * 8];
        f32x4 acc = {0.f, 0.f, 0.f, 0.f};
        #pragma unroll
        for (int kt = 0; kt < SEQ; kt += 32) {
            bf16x8 af = *(const bf16x8*)(apm + kt);
            bf16x8 bf = *(const bf16x8*)(bp + kt);
            acc = __builtin_amdgcn_mfma_f32_16x16x32_bf16(af, bf, acc, 0, 0, 0);
        }
        const int b = bh >> 3, hh = bh & 7;
        const int c = wv * 16 + r;
        const int col = hh * HC + c;
        const float bpn = bproj[col];
        #pragma unroll
        for (int i = 0; i < 4; ++i) {
            const int tl = q * 4 + i;
            const int t  = qbase + tl;
            const float v = acc[i] * pinv[tl];
            const int idx = ((b * SEQ + t) * DM) + col;
            const float res = xin[idx] + v;
            x1[idx]  = res;
            out[idx] = res + bpn;      // base: x1 + bproj; K3 atomically adds h@Wproj
        }
    }
}

// ---------------------------------------------------------------------------
// K3: fused MLP, grid-preserving split-K. 256 blocks x 256 thr:
// block = (m-tile mt = bid&63, slab ns = bid>>6). FC computes h-slab
// h[16][ns*256..+256) -> LDS bf16 [16][264]; PROJ computes the k-slice
// partial h_slab @ Wproj[:, ns*256..+256) and atomicAdds into out.
// Weight traffic/block = 256 KB (vs 1 MB in round-7's 64-block version).
// ---------------------------------------------------------------------------
#define HSTR 264

__global__ __launch_bounds__(256)
void mlp_k(const float* __restrict__ X1, const char* __restrict__ wsb,
           const float* __restrict__ bfc, float* __restrict__ out)
{
    __shared__ __bf16 hs[16 * HSTR];   // 8.4 KB
    const __bf16* Wf = (const __bf16*)(wsb + B_WFCT);
    const __bf16* Wp = (const __bf16*)(wsb + B_WPJT);

    const int tid  = threadIdx.x;
    const int lane = tid & 63;
    const int wv   = tid >> 6;
    const int mt   = blockIdx.x & 63;
    const int ns   = blockIdx.x >> 6;            // k/n slab 0..3
    const int m0   = mt * 16;
    const int r    = lane & 15, q = lane >> 4;

    // ---- FC phase: h[16][ns*256 .. +256) ----
    {
        const float* ap = X1 + (size_t)(m0 + r) * DM + q * 8;
        f32x4 acc[4] = {};
        #pragma unroll
        for (int kt = 0; kt < DM; kt += 32) {
            float4 a0 = *(const float4*)(ap + kt);
            float4 a1 = *(const float4*)(ap + kt + 4);
            bf16x8 af;
            af[0] = (__bf16)a0.x; af[1] = (__bf16)a0.y; af[2] = (__bf16)a0.z; af[3] = (__bf16)a0.w;
            af[4] = (__bf16)a1.x; af[5] = (__bf16)a1.y; af[6] = (__bf16)a1.z; af[7] = (__bf16)a1.w;
            #pragma unroll
            for (int nt = 0; nt < 4; ++nt) {
                const int n0 = ns * 256 + (wv * 4 + nt) * 16;       // global h col
                bf16x8 bf = *(const bf16x8*)(Wf + (size_t)(n0 + r) * DM + q * 8 + kt);
                acc[nt] = __builtin_amdgcn_mfma_f32_16x16x32_bf16(af, bf, acc[nt], 0, 0, 0);
            }
        }
        #pragma unroll
        for (int nt = 0; nt < 4; ++nt) {
            const int nl = (wv * 4 + nt) * 16 + r;                  // local 0..255
            const float bn = bfc[ns * 256 + nl];
            #pragma unroll
            for (int i = 0; i < 4; ++i)
                hs[(q * 4 + i) * HSTR + nl] = (__bf16)qgelu(acc[nt][i] + bn);
        }
    }
    __syncthreads();

    // ---- PROJ phase: out[m0..+16][wv*64..+64) += h_slab @ Wp k-slice ----
    {
        f32x4 acc[4] = {};
        const __bf16* al = &hs[r * HSTR + q * 8];                   // A row = m
        #pragma unroll
        for (int kt = 0; kt < 256; kt += 32) {
            bf16x8 af = *(const bf16x8*)(al + kt);
            #pragma unroll
            for (int nt = 0; nt < 4; ++nt) {
                const int n0 = wv * 64 + nt * 16;
                bf16x8 bf = *(const bf16x8*)(Wp + (size_t)(n0 + r) * 1024 +
                                             ns * 256 + q * 8 + kt);
                acc[nt] = __builtin_amdgcn_mfma_f32_16x16x32_bf16(af, bf, acc[nt], 0, 0, 0);
            }
        }
        #pragma unroll
        for (int nt = 0; nt < 4; ++nt) {
            const int n = wv * 64 + nt * 16 + r;
            #pragma unroll
            for (int i = 0; i < 4; ++i) {
                const int m = m0 + q * 4 + i;
                atomicAdd(&out[(size_t)m * DM + n], acc[nt][i]);
            }
        }
    }
}

// ---------------------------------------------------------------------------
extern "C" void kernel_launch(void* const* d_in, const int* in_sizes, int n_in,
                              void* d_out, int out_size, void* d_ws, size_t ws_size,
                              hipStream_t stream)
{
    (void)in_sizes; (void)n_in; (void)out_size; (void)ws_size;
    const float* x     = (const float*)d_in[0];
    const float* Wqkv  = (const float*)d_in[1];
    const float* bqkv  = (const float*)d_in[2];
    const float* Wfc   = (const float*)d_in[3];
    const float* bfc   = (const float*)d_in[4];
    const float* Wproj = (const float*)d_in[5];
    const float* bproj = (const float*)d_in[6];
    float* out = (float*)d_out;
    char*  wsb = (char*)d_ws;
    float* x1  = (float*)(wsb + B_X1);

    // K1: QKV GEMM (strided W) + side-car Wfc/Wproj transposes
    qkv_k<<<896, 256, 0, stream>>>(x, Wqkv, bqkv, Wfc, Wproj, wsb);

    // K2: attention + residual -> x1; pre-init out = x1 + bproj
    attn_k<<<512, 512, 0, stream>>>(wsb, x, x1, bproj, out);

    // K3: out += qgelu(x1@Wfc+b) @ Wproj   (split-K x4, atomic accumulate)
    mlp_k<<<256, 256, 0, stream>>>(x1, wsb, bfc, out);
}